// Round 3
// baseline (130.710 us; speedup 1.0000x reference)
//
#include <hip/hip_runtime.h>

#define BDIM 256
#define HH 256
#define WW 256
#define NF 64
#define NH 8

// round-to-nearest-even fp32 -> bf16 bits
__device__ __forceinline__ unsigned short f2bf(float f) {
  const unsigned u = __float_as_uint(f);
  return (unsigned short)((u + 0x7fffu + ((u >> 16) & 1u)) >> 16);
}
// bf16 bits -> fp32
__device__ __forceinline__ float bf2f(unsigned short b) {
  return __uint_as_float(((unsigned)b) << 16);
}

struct __align__(16) Smem {
  unsigned short x1t[NF * WW];   // 32768 B  x1 row rounded to bf16, [c][w]
  float kbuf[WW * NH];           // 8192 B   [w][d]
  float vbuf[WW * NH];           // 8192 B   [w][d]
  float qwp[NH * NF];            // q_w * g1
  float vwp[NH * NF];            // v_w * g1
  float kwp[NH * NF];            // k_w * g2
  float fanw[NF * NH];           // [c][d]
  float g1[NF], b1[NF], g2[NF], b2v[NF];
  float gamma[NF], fanb[NF];
  float Sq1[NH], Sq0[NH], Sk1[NH], Sk0[NH], Sv1[NH], Sv0[NH];
  float bsel[NH];
};

__global__ __launch_bounds__(BDIM, 2)
void cc_attn_kernel(const float* __restrict__ x1,
                    const float* __restrict__ x2,
                    const float* __restrict__ q_w,
                    const float* __restrict__ q_b,
                    const float* __restrict__ k_w,
                    const float* __restrict__ k_b,
                    const float* __restrict__ v_w,
                    const float* __restrict__ v_b,
                    const float* __restrict__ bias,
                    const float* __restrict__ sel_w,
                    const float* __restrict__ sel_b,
                    const float* __restrict__ fan_w,
                    const float* __restrict__ fan_b,
                    const float* __restrict__ gma,
                    const float* __restrict__ ln1w,
                    const float* __restrict__ ln1b,
                    const float* __restrict__ ln2w,
                    const float* __restrict__ ln2b,
                    float* __restrict__ out)
{
  __shared__ Smem s;
  const int tid = threadIdx.x;
  const int w = tid;
  const int b = blockIdx.x >> 8;
  const int h = blockIdx.x & 255;

  // ---- phase 0: small per-channel params into LDS ----
  if (tid < NF) {
    s.g1[tid]    = ln1w[tid];
    s.b1[tid]    = ln1b[tid];
    s.g2[tid]    = ln2w[tid];
    s.b2v[tid]   = ln2b[tid];
    s.gamma[tid] = gma[tid];
    s.fanb[tid]  = fan_b[tid];
  }
  __syncthreads();

  // ---- phase 1: derived (LN-gain-folded) projection weights ----
  for (int i = tid; i < NH * NF; i += BDIM) {
    const int c = i & (NF - 1);
    s.qwp[i]  = q_w[i] * s.g1[c];
    s.vwp[i]  = v_w[i] * s.g1[c];
    s.kwp[i]  = k_w[i] * s.g2[c];
    s.fanw[i] = fan_w[i];
  }
  __syncthreads();

  // ---- phase 2a: stage x1 row (all 64 channels) into LDS as bf16 ----
  {
    const size_t base = ((size_t)(b * NF) * HH + h) * WW;
    for (int j = tid; j < NF * WW / 4; j += BDIM) {   // 4096 float4 chunks
      const int c  = j >> 6;
      const int o4 = (j & 63) * 4;
      const float4 val = *reinterpret_cast<const float4*>(x1 + base + (size_t)c * (HH * WW) + o4);
      ushort4 pk;
      pk.x = f2bf(val.x);
      pk.y = f2bf(val.y);
      pk.z = f2bf(val.z);
      pk.w = f2bf(val.w);
      *reinterpret_cast<ushort4*>(&s.x1t[c * WW + o4]) = pk;
    }
  }

  // ---- phase 2b: per-head reduction constants (threads 0..7) ----
  if (tid < NH) {
    const int d = tid;
    float s1q = 0, s0q = 0, s1k = 0, s0k = 0, s1v = 0, s0v = 0, bs = 0;
    for (int c = 0; c < NF; c++) {
      s1q += s.qwp[d * NF + c]; s0q += s.b1[c]  * q_w[d * NF + c];
      s1k += s.kwp[d * NF + c]; s0k += s.b2v[c] * k_w[d * NF + c];
      s1v += s.vwp[d * NF + c]; s0v += s.b1[c]  * v_w[d * NF + c];
      bs  += bias[c] * sel_w[d * NF + c];
    }
    s.Sq1[d] = s1q; s.Sq0[d] = s0q + q_b[d];
    s.Sk1[d] = s1k; s.Sk0[d] = s0k + k_b[d];
    s.Sv1[d] = s1v; s.Sv0[d] = s0v + v_b[d];
    s.bsel[d] = bs + sel_b[d];
  }

  // ---- phase 2c: single streaming pass over x2 (registers only) ----
  float sum2 = 0.f, ss2 = 0.f;
  float tk[NH] = {};
  {
    const float* p = x2 + ((size_t)(b * NF) * HH + h) * WW + w;
    for (int c = 0; c < NF; c++) {
      const float xv = p[(size_t)c * (HH * WW)];
      sum2 += xv; ss2 += xv * xv;
      #pragma unroll
      for (int d = 0; d < NH; d++) tk[d] += xv * s.kwp[d * NF + c];
    }
  }
  __syncthreads();

  // ---- phase 3: x1 stats + q/v projections from LDS ----
  float sum1 = 0.f, ss1 = 0.f;
  float tq[NH] = {}, tv[NH] = {};
  for (int c = 0; c < NF; c++) {
    const float xv = bf2f(s.x1t[c * WW + w]);
    sum1 += xv; ss1 += xv * xv;
    #pragma unroll
    for (int d = 0; d < NH; d++) {
      tq[d] += xv * s.qwp[d * NF + c];
      tv[d] += xv * s.vwp[d * NF + c];
    }
  }
  const float mu1   = sum1 * (1.f / NF);
  const float rstd1 = rsqrtf(ss1 * (1.f / NF) - mu1 * mu1 + 1e-5f);
  const float mu2   = sum2 * (1.f / NF);
  const float rstd2 = rsqrtf(ss2 * (1.f / NF) - mu2 * mu2 + 1e-5f);

  const float QS = 0.125f * 1.44269504088896340736f;  // SCALE * log2(e)
  float q2[NH];
  #pragma unroll
  for (int d = 0; d < NH; d++) {
    q2[d] = (rstd1 * (tq[d] - mu1 * s.Sq1[d]) + s.Sq0[d]) * QS;
    s.vbuf[w * NH + d] = rstd1 * (tv[d] - mu1 * s.Sv1[d]) + s.Sv0[d];
    s.kbuf[w * NH + d] = rstd2 * (tk[d] - mu2 * s.Sk1[d]) + s.Sk0[d];
  }
  __syncthreads();

  // ---- phase 4: row attention, two-pass softmax (log2 domain) ----
  float mA = -1e30f, mB = -1e30f;
  for (int u = 0; u < WW; u += 2) {
    const float4* kp = reinterpret_cast<const float4*>(&s.kbuf[u * NH]);
    const float4 a0 = kp[0], a1 = kp[1], c0 = kp[2], c1 = kp[3];
    const float sA = q2[0]*a0.x + q2[1]*a0.y + q2[2]*a0.z + q2[3]*a0.w
                   + q2[4]*a1.x + q2[5]*a1.y + q2[6]*a1.z + q2[7]*a1.w;
    const float sB = q2[0]*c0.x + q2[1]*c0.y + q2[2]*c0.z + q2[3]*c0.w
                   + q2[4]*c1.x + q2[5]*c1.y + q2[6]*c1.z + q2[7]*c1.w;
    mA = fmaxf(mA, sA); mB = fmaxf(mB, sB);
  }
  const float m = fmaxf(mA, mB);

  float lA = 0.f, lB = 0.f;
  float accA[NH] = {}, accB[NH] = {};
  for (int u = 0; u < WW; u += 2) {
    const float4* kp = reinterpret_cast<const float4*>(&s.kbuf[u * NH]);
    const float4 a0 = kp[0], a1 = kp[1], c0 = kp[2], c1 = kp[3];
    const float sA = q2[0]*a0.x + q2[1]*a0.y + q2[2]*a0.z + q2[3]*a0.w
                   + q2[4]*a1.x + q2[5]*a1.y + q2[6]*a1.z + q2[7]*a1.w;
    const float sB = q2[0]*c0.x + q2[1]*c0.y + q2[2]*c0.z + q2[3]*c0.w
                   + q2[4]*c1.x + q2[5]*c1.y + q2[6]*c1.z + q2[7]*c1.w;
    const float pA = __builtin_amdgcn_exp2f(sA - m);
    const float pB = __builtin_amdgcn_exp2f(sB - m);
    lA += pA; lB += pB;
    const float4* vp = reinterpret_cast<const float4*>(&s.vbuf[u * NH]);
    const float4 va0 = vp[0], va1 = vp[1], vb0 = vp[2], vb1 = vp[3];
    accA[0] += pA * va0.x; accA[1] += pA * va0.y; accA[2] += pA * va0.z; accA[3] += pA * va0.w;
    accA[4] += pA * va1.x; accA[5] += pA * va1.y; accA[6] += pA * va1.z; accA[7] += pA * va1.w;
    accB[0] += pB * vb0.x; accB[1] += pB * vb0.y; accB[2] += pB * vb0.z; accB[3] += pB * vb0.w;
    accB[4] += pB * vb1.x; accB[5] += pB * vb1.y; accB[6] += pB * vb1.z; accB[7] += pB * vb1.w;
  }
  const float rl = 1.0f / (lA + lB);
  float mp[NH];
  #pragma unroll
  for (int d = 0; d < NH; d++) mp[d] = (accA[d] + accB[d]) * rl + s.bsel[d];

  // ---- phase 5: fan-out + gated residual, write NCHW fp32 ----
  {
    const size_t obase = ((size_t)(b * NF) * HH + h) * WW + w;
    for (int c = 0; c < NF; c++) {
      const float4* fp = reinterpret_cast<const float4*>(&s.fanw[c * NH]);
      const float4 f0 = fp[0], f1 = fp[1];
      const float fo = mp[0]*f0.x + mp[1]*f0.y + mp[2]*f0.z + mp[3]*f0.w
                     + mp[4]*f1.x + mp[5]*f1.y + mp[6]*f1.z + mp[7]*f1.w + s.fanb[c];
      const float xv  = bf2f(s.x1t[c * WW + w]);
      const float x1n = (xv - mu1) * rstd1 * s.g1[c] + s.b1[c];
      out[obase + (size_t)c * (HH * WW)] = x1n + s.gamma[c] * fo;
    }
  }
}

extern "C" void kernel_launch(void* const* d_in, const int* in_sizes, int n_in,
                              void* d_out, int out_size, void* d_ws, size_t ws_size,
                              hipStream_t stream) {
  (void)in_sizes; (void)n_in; (void)d_ws; (void)ws_size; (void)out_size;
  const float* x1    = (const float*)d_in[0];
  const float* x2    = (const float*)d_in[1];
  const float* q_w   = (const float*)d_in[2];
  const float* q_b   = (const float*)d_in[3];
  const float* k_w   = (const float*)d_in[4];
  const float* k_b   = (const float*)d_in[5];
  const float* v_w   = (const float*)d_in[6];
  const float* v_b   = (const float*)d_in[7];
  const float* bias  = (const float*)d_in[8];
  const float* sel_w = (const float*)d_in[9];
  const float* sel_b = (const float*)d_in[10];
  const float* fan_w = (const float*)d_in[11];
  const float* fan_b = (const float*)d_in[12];
  const float* gma   = (const float*)d_in[13];
  const float* ln1w  = (const float*)d_in[14];
  const float* ln1b  = (const float*)d_in[15];
  const float* ln2w  = (const float*)d_in[16];
  const float* ln2b  = (const float*)d_in[17];

  hipLaunchKernelGGL(cc_attn_kernel, dim3(4 * HH), dim3(BDIM), 0, stream,
                     x1, x2, q_w, q_b, k_w, k_b, v_w, v_b, bias, sel_w, sel_b,
                     fan_w, fan_b, gma, ln1w, ln1b, ln2w, ln2b,
                     (float*)d_out);
}

// Round 4
// 110.969 us; speedup vs baseline: 1.1779x; 1.1779x over previous
//
#include <hip/hip_runtime.h>

#define BDIM 256
#define HH 256
#define WW 256
#define NF 64
#define NH 8

struct __align__(16) Smem {
  float kbuf[WW * NH];           // 8192 B   [w][d]
  float vbuf[WW * NH];           // 8192 B   [w][d]
  float qwp[NH * NF];            // q_w * g1
  float vwp[NH * NF];            // v_w * g1
  float kwp[NH * NF];            // k_w * g2
  float fanw[NF * NH];           // [c][d]
  float g1[NF], b1[NF], g2[NF], b2v[NF];
  float gamma[NF], fanb[NF];
  float Sq1[NH], Sq0[NH], Sk1[NH], Sk0[NH], Sv1[NH], Sv0[NH];
  float bsel[NH];
};

__global__ __launch_bounds__(BDIM, 4)
void cc_attn_kernel(const float* __restrict__ x1,
                    const float* __restrict__ x2,
                    const float* __restrict__ q_w,
                    const float* __restrict__ q_b,
                    const float* __restrict__ k_w,
                    const float* __restrict__ k_b,
                    const float* __restrict__ v_w,
                    const float* __restrict__ v_b,
                    const float* __restrict__ bias,
                    const float* __restrict__ sel_w,
                    const float* __restrict__ sel_b,
                    const float* __restrict__ fan_w,
                    const float* __restrict__ fan_b,
                    const float* __restrict__ gma,
                    const float* __restrict__ ln1w,
                    const float* __restrict__ ln1b,
                    const float* __restrict__ ln2w,
                    const float* __restrict__ ln2b,
                    float* __restrict__ out)
{
  __shared__ Smem s;
  const int tid = threadIdx.x;
  const int w = tid;
  const int b = blockIdx.x >> 8;
  const int h = blockIdx.x & 255;

  // ---- phase 0: small per-channel params into LDS ----
  if (tid < NF) {
    s.g1[tid]    = ln1w[tid];
    s.b1[tid]    = ln1b[tid];
    s.g2[tid]    = ln2w[tid];
    s.b2v[tid]   = ln2b[tid];
    s.gamma[tid] = gma[tid];
    s.fanb[tid]  = fan_b[tid];
  }
  __syncthreads();

  // ---- phase 1: derived (LN-gain-folded) projection weights ----
  for (int i = tid; i < NH * NF; i += BDIM) {
    const int c = i & (NF - 1);
    s.qwp[i]  = q_w[i] * s.g1[c];
    s.vwp[i]  = v_w[i] * s.g1[c];
    s.kwp[i]  = k_w[i] * s.g2[c];
    s.fanw[i] = fan_w[i];
  }
  __syncthreads();

  // ---- phase 2a: per-head reduction constants (threads 0..7) ----
  if (tid < NH) {
    const int d = tid;
    float s1q = 0, s0q = 0, s1k = 0, s0k = 0, s1v = 0, s0v = 0, bs = 0;
    for (int c = 0; c < NF; c++) {
      s1q += s.qwp[d * NF + c]; s0q += s.b1[c]  * q_w[d * NF + c];
      s1k += s.kwp[d * NF + c]; s0k += s.b2v[c] * k_w[d * NF + c];
      s1v += s.vwp[d * NF + c]; s0v += s.b1[c]  * v_w[d * NF + c];
      bs  += bias[c] * sel_w[d * NF + c];
    }
    s.Sq1[d] = s1q; s.Sq0[d] = s0q + q_b[d];
    s.Sk1[d] = s1k; s.Sk0[d] = s0k + k_b[d];
    s.Sv1[d] = s1v; s.Sv0[d] = s0v + v_b[d];
    s.bsel[d] = bs + sel_b[d];
  }

  const size_t base = ((size_t)(b * NF) * HH + h) * WW + w;

  // ---- phase 2b: single streaming pass over x2 (registers only) ----
  float sum2 = 0.f, ss2 = 0.f;
  float tk[NH] = {};
  {
    const float* p = x2 + base;
    #pragma unroll 4
    for (int c = 0; c < NF; c++) {
      const float xv = p[(size_t)c * (HH * WW)];
      sum2 += xv; ss2 += xv * xv;
      #pragma unroll
      for (int d = 0; d < NH; d++) tk[d] += xv * s.kwp[d * NF + c];
    }
  }

  // ---- phase 3: streaming pass over x1: stats + q/v projections ----
  float sum1 = 0.f, ss1 = 0.f;
  float tq[NH] = {}, tv[NH] = {};
  {
    const float* p = x1 + base;
    #pragma unroll 4
    for (int c = 0; c < NF; c++) {
      const float xv = p[(size_t)c * (HH * WW)];
      sum1 += xv; ss1 += xv * xv;
      #pragma unroll
      for (int d = 0; d < NH; d++) {
        tq[d] += xv * s.qwp[d * NF + c];
        tv[d] += xv * s.vwp[d * NF + c];
      }
    }
  }
  const float mu1   = sum1 * (1.f / NF);
  const float rstd1 = rsqrtf(ss1 * (1.f / NF) - mu1 * mu1 + 1e-5f);
  const float mu2   = sum2 * (1.f / NF);
  const float rstd2 = rsqrtf(ss2 * (1.f / NF) - mu2 * mu2 + 1e-5f);

  __syncthreads();  // kbuf/vbuf free from any previous iteration's readers

  const float QS = 0.125f * 1.44269504088896340736f;  // SCALE * log2(e)
  float q2[NH];
  #pragma unroll
  for (int d = 0; d < NH; d++) {
    q2[d] = (rstd1 * (tq[d] - mu1 * s.Sq1[d]) + s.Sq0[d]) * QS;
    s.vbuf[w * NH + d] = rstd1 * (tv[d] - mu1 * s.Sv1[d]) + s.Sv0[d];
    s.kbuf[w * NH + d] = rstd2 * (tk[d] - mu2 * s.Sk1[d]) + s.Sk0[d];
  }
  __syncthreads();

  // ---- phase 4: row attention, two-pass softmax (log2 domain) ----
  float mA = -1e30f, mB = -1e30f;
  for (int u = 0; u < WW; u += 2) {
    const float4* kp = reinterpret_cast<const float4*>(&s.kbuf[u * NH]);
    const float4 a0 = kp[0], a1 = kp[1], c0 = kp[2], c1 = kp[3];
    const float sA = q2[0]*a0.x + q2[1]*a0.y + q2[2]*a0.z + q2[3]*a0.w
                   + q2[4]*a1.x + q2[5]*a1.y + q2[6]*a1.z + q2[7]*a1.w;
    const float sB = q2[0]*c0.x + q2[1]*c0.y + q2[2]*c0.z + q2[3]*c0.w
                   + q2[4]*c1.x + q2[5]*c1.y + q2[6]*c1.z + q2[7]*c1.w;
    mA = fmaxf(mA, sA); mB = fmaxf(mB, sB);
  }
  const float m = fmaxf(mA, mB);

  float lA = 0.f, lB = 0.f;
  float accA[NH] = {}, accB[NH] = {};
  for (int u = 0; u < WW; u += 2) {
    const float4* kp = reinterpret_cast<const float4*>(&s.kbuf[u * NH]);
    const float4 a0 = kp[0], a1 = kp[1], c0 = kp[2], c1 = kp[3];
    const float sA = q2[0]*a0.x + q2[1]*a0.y + q2[2]*a0.z + q2[3]*a0.w
                   + q2[4]*a1.x + q2[5]*a1.y + q2[6]*a1.z + q2[7]*a1.w;
    const float sB = q2[0]*c0.x + q2[1]*c0.y + q2[2]*c0.z + q2[3]*c0.w
                   + q2[4]*c1.x + q2[5]*c1.y + q2[6]*c1.z + q2[7]*c1.w;
    const float pA = __builtin_amdgcn_exp2f(sA - m);
    const float pB = __builtin_amdgcn_exp2f(sB - m);
    lA += pA; lB += pB;
    const float4* vp = reinterpret_cast<const float4*>(&s.vbuf[u * NH]);
    const float4 va0 = vp[0], va1 = vp[1], vb0 = vp[2], vb1 = vp[3];
    accA[0] += pA * va0.x; accA[1] += pA * va0.y; accA[2] += pA * va0.z; accA[3] += pA * va0.w;
    accA[4] += pA * va1.x; accA[5] += pA * va1.y; accA[6] += pA * va1.z; accA[7] += pA * va1.w;
    accB[0] += pB * vb0.x; accB[1] += pB * vb0.y; accB[2] += pB * vb0.z; accB[3] += pB * vb0.w;
    accB[4] += pB * vb1.x; accB[5] += pB * vb1.y; accB[6] += pB * vb1.z; accB[7] += pB * vb1.w;
  }
  const float rl = 1.0f / (lA + lB);
  float mp[NH];
  #pragma unroll
  for (int d = 0; d < NH; d++) mp[d] = (accA[d] + accB[d]) * rl + s.bsel[d];

  // ---- phase 5: fan-out + gated residual (x1 re-read from L2/L3) ----
  {
    const float* p = x1 + base;
    #pragma unroll 4
    for (int c = 0; c < NF; c++) {
      const float4* fp = reinterpret_cast<const float4*>(&s.fanw[c * NH]);
      const float4 f0 = fp[0], f1 = fp[1];
      const float fo = mp[0]*f0.x + mp[1]*f0.y + mp[2]*f0.z + mp[3]*f0.w
                     + mp[4]*f1.x + mp[5]*f1.y + mp[6]*f1.z + mp[7]*f1.w + s.fanb[c];
      const float xv  = p[(size_t)c * (HH * WW)];
      const float x1n = (xv - mu1) * rstd1 * s.g1[c] + s.b1[c];
      out[base + (size_t)c * (HH * WW)] = x1n + s.gamma[c] * fo;
    }
  }
}

extern "C" void kernel_launch(void* const* d_in, const int* in_sizes, int n_in,
                              void* d_out, int out_size, void* d_ws, size_t ws_size,
                              hipStream_t stream) {
  (void)in_sizes; (void)n_in; (void)d_ws; (void)ws_size; (void)out_size;
  const float* x1    = (const float*)d_in[0];
  const float* x2    = (const float*)d_in[1];
  const float* q_w   = (const float*)d_in[2];
  const float* q_b   = (const float*)d_in[3];
  const float* k_w   = (const float*)d_in[4];
  const float* k_b   = (const float*)d_in[5];
  const float* v_w   = (const float*)d_in[6];
  const float* v_b   = (const float*)d_in[7];
  const float* bias  = (const float*)d_in[8];
  const float* sel_w = (const float*)d_in[9];
  const float* sel_b = (const float*)d_in[10];
  const float* fan_w = (const float*)d_in[11];
  const float* fan_b = (const float*)d_in[12];
  const float* gma   = (const float*)d_in[13];
  const float* ln1w  = (const float*)d_in[14];
  const float* ln1b  = (const float*)d_in[15];
  const float* ln2w  = (const float*)d_in[16];
  const float* ln2b  = (const float*)d_in[17];

  hipLaunchKernelGGL(cc_attn_kernel, dim3(4 * HH), dim3(BDIM), 0, stream,
                     x1, x2, q_w, q_b, k_w, k_b, v_w, v_b, bias, sel_w, sel_b,
                     fan_w, fan_b, gma, ln1w, ln1b, ln2w, ln2b,
                     (float*)d_out);
}

// Round 5
// 98.121 us; speedup vs baseline: 1.3321x; 1.1309x over previous
//
#include <hip/hip_runtime.h>

#define BDIM 512
#define HH 256
#define WW 256
#define NF 64
#define NH 8
#define HW (HH * WW)

struct __align__(16) Smem {
  // kbuf live: projection -> end of attention loop (barrier 4). mpst written after barrier 4.
  union { float kbuf[WW * NH]; float mpst[WW * NH]; } kb;      // 8 KB
  float vbuf[WW * NH];                                          // 8 KB (live through attention)
  // qbuf live: projection -> q2 register load (barrier 3). part written after barrier 3.
  union { float qbuf[WW * NH]; float part[WW][NH + 1]; } qb;    // 9.25 KB
  float murst[WW][2];                                           // mu1, rstd1 per pixel (phase 5)
  float Sq1[NH], Sq0[NH], Sk1[NH], Sk0[NH], Sv1[NH], Sv0[NH], bsel[NH];
};

__global__ __launch_bounds__(BDIM, 8)
void cc_attn_kernel(const float* __restrict__ x1,
                    const float* __restrict__ x2,
                    const float* __restrict__ q_w,
                    const float* __restrict__ q_b,
                    const float* __restrict__ k_w,
                    const float* __restrict__ k_b,
                    const float* __restrict__ v_w,
                    const float* __restrict__ v_b,
                    const float* __restrict__ bias,
                    const float* __restrict__ sel_w,
                    const float* __restrict__ sel_b,
                    const float* __restrict__ fan_w,
                    const float* __restrict__ fan_b,
                    const float* __restrict__ gma,
                    const float* __restrict__ ln1w,
                    const float* __restrict__ ln1b,
                    const float* __restrict__ ln2w,
                    const float* __restrict__ ln2b,
                    float* __restrict__ out)
{
  __shared__ Smem s;
  const int tid  = threadIdx.x;
  const int role = tid >> 8;         // 0: x2/K side (waves 0-3), 1: x1/Q,V side (waves 4-7)
  const int pix  = tid & 255;        // pixel this thread projects
  const int b = blockIdx.x >> 8;
  const int h = blockIdx.x & 255;
  const size_t rowbase = ((size_t)(b * NF) * HH + h) * WW;
  const size_t base = rowbase + pix;

  // ---- per-head reduction constants (threads 0..7; vector loads, small) ----
  if (tid < NH) {
    const int d = tid;
    float s1q = 0, s0q = 0, s1k = 0, s0k = 0, s1v = 0, s0v = 0, bs = 0;
    for (int c = 0; c < NF; c++) {
      const float qw = q_w[d * NF + c], kw = k_w[d * NF + c], vw = v_w[d * NF + c];
      s1q += ln1w[c] * qw; s0q += ln1b[c] * qw;
      s1k += ln2w[c] * kw; s0k += ln2b[c] * kw;
      s1v += ln1w[c] * vw; s0v += ln1b[c] * vw;
      bs  += bias[c] * sel_w[d * NF + c];
    }
    s.Sq1[d] = s1q; s.Sq0[d] = s0q + q_b[d];
    s.Sk1[d] = s1k; s.Sk0[d] = s0k + k_b[d];
    s.Sv1[d] = s1v; s.Sv0[d] = s0v + v_b[d];
    s.bsel[d] = bs + sel_b[d];
  }

  // ---- streaming projection pass (role-split; weights via uniform s_loads) ----
  float sum = 0.f, ss = 0.f;
  float ta[NH] = {}, tb[NH] = {};
  if (role == 0) {
    const float* p = x2 + base;
    #pragma unroll 4
    for (int c = 0; c < NF; c++) {
      const float xv = p[(size_t)c * HW];
      const float yv = xv * ln2w[c];
      sum += xv; ss += xv * xv;
      #pragma unroll
      for (int d = 0; d < NH; d++) ta[d] += yv * k_w[d * NF + c];
    }
  } else {
    const float* p = x1 + base;
    #pragma unroll 4
    for (int c = 0; c < NF; c++) {
      const float xv = p[(size_t)c * HW];
      const float yv = xv * ln1w[c];
      sum += xv; ss += xv * xv;
      #pragma unroll
      for (int d = 0; d < NH; d++) {
        ta[d] += yv * q_w[d * NF + c];
        tb[d] += yv * v_w[d * NF + c];
      }
    }
  }
  const float mu   = sum * (1.f / NF);
  const float rstd = rsqrtf(ss * (1.f / NF) - mu * mu + 1e-5f);
  if (role == 1) { s.murst[pix][0] = mu; s.murst[pix][1] = rstd; }

  __syncthreads();   // #1: head consts visible

  const float QS = 0.125f * 1.44269504088896340736f;  // SCALE * log2(e)
  if (role == 0) {
    #pragma unroll
    for (int d = 0; d < NH; d++)
      s.kb.kbuf[pix * NH + d] = rstd * (ta[d] - mu * s.Sk1[d]) + s.Sk0[d];
  } else {
    #pragma unroll
    for (int d = 0; d < NH; d++) {
      s.qb.qbuf[pix * NH + d] = (rstd * (ta[d] - mu * s.Sq1[d]) + s.Sq0[d]) * QS;
      s.vbuf[pix * NH + d]    =  rstd * (tb[d] - mu * s.Sv1[d]) + s.Sv0[d];
    }
  }

  __syncthreads();   // #2: kbuf/qbuf/vbuf ready

  // ---- attention: query qg, keys [role*128, role*128+128), no max pass ----
  const int qg = pix;
  float q2[NH];
  {
    const float4* qp = reinterpret_cast<const float4*>(&s.qb.qbuf[qg * NH]);
    const float4 q0 = qp[0], q1 = qp[1];
    q2[0] = q0.x; q2[1] = q0.y; q2[2] = q0.z; q2[3] = q0.w;
    q2[4] = q1.x; q2[5] = q1.y; q2[6] = q1.z; q2[7] = q1.w;
  }
  __syncthreads();   // #3: qbuf dead -> part region free for writes

  float lA = 0.f, lB = 0.f;
  float accA[NH] = {}, accB[NH] = {};
  const int u0 = role * 128;
  for (int u = 0; u < 128; u += 2) {
    const float4* kp = reinterpret_cast<const float4*>(&s.kb.kbuf[(u0 + u) * NH]);
    const float4 a0 = kp[0], a1 = kp[1], c0 = kp[2], c1 = kp[3];
    const float sA = q2[0]*a0.x + q2[1]*a0.y + q2[2]*a0.z + q2[3]*a0.w
                   + q2[4]*a1.x + q2[5]*a1.y + q2[6]*a1.z + q2[7]*a1.w;
    const float sB = q2[0]*c0.x + q2[1]*c0.y + q2[2]*c0.z + q2[3]*c0.w
                   + q2[4]*c1.x + q2[5]*c1.y + q2[6]*c1.z + q2[7]*c1.w;
    const float pA = __builtin_amdgcn_exp2f(sA);
    const float pB = __builtin_amdgcn_exp2f(sB);
    lA += pA; lB += pB;
    const float4* vp = reinterpret_cast<const float4*>(&s.vbuf[(u0 + u) * NH]);
    const float4 va0 = vp[0], va1 = vp[1], vb0 = vp[2], vb1 = vp[3];
    accA[0] += pA * va0.x; accA[1] += pA * va0.y; accA[2] += pA * va0.z; accA[3] += pA * va0.w;
    accA[4] += pA * va1.x; accA[5] += pA * va1.y; accA[6] += pA * va1.z; accA[7] += pA * va1.w;
    accB[0] += pB * vb0.x; accB[1] += pB * vb0.y; accB[2] += pB * vb0.z; accB[3] += pB * vb0.w;
    accB[4] += pB * vb1.x; accB[5] += pB * vb1.y; accB[6] += pB * vb1.z; accB[7] += pB * vb1.w;
  }
  const float lpart = lA + lB;
  float acc[NH];
  #pragma unroll
  for (int d = 0; d < NH; d++) acc[d] = accA[d] + accB[d];

  if (role == 1) {
    #pragma unroll
    for (int d = 0; d < NH; d++) s.qb.part[qg][d] = acc[d];
    s.qb.part[qg][NH] = lpart;
  }
  __syncthreads();   // #4: partials ready; kbuf dead -> mpst region free

  float mp[NH];
  if (role == 0) {
    const float rl = 1.0f / (lpart + s.qb.part[qg][NH]);
    #pragma unroll
    for (int d = 0; d < NH; d++) {
      mp[d] = (acc[d] + s.qb.part[qg][d]) * rl + s.bsel[d];
      s.kb.mpst[qg * NH + d] = mp[d];
    }
  }
  __syncthreads();   // #5: mpst ready
  if (role == 1) {
    const float4* mq = reinterpret_cast<const float4*>(&s.kb.mpst[qg * NH]);
    const float4 m0 = mq[0], m1v = mq[1];
    mp[0] = m0.x; mp[1] = m0.y; mp[2] = m0.z; mp[3] = m0.w;
    mp[4] = m1v.x; mp[5] = m1v.y; mp[6] = m1v.z; mp[7] = m1v.w;
  }

  // ---- fan-out + gated residual: pair splits the 64 channels ----
  {
    const float m1 = s.murst[qg][0];
    const float r1 = s.murst[qg][1];
    const int c0 = role * 32;
    const size_t qbase = rowbase + qg;
    const float* p = x1 + qbase;
    #pragma unroll 4
    for (int cc = 0; cc < 32; cc++) {
      const int c = c0 + cc;
      float fo = fan_b[c];
      #pragma unroll
      for (int d = 0; d < NH; d++) fo += mp[d] * fan_w[c * NH + d];
      const float xv  = p[(size_t)c * HW];
      const float x1n = (xv - m1) * r1 * ln1w[c] + ln1b[c];
      out[qbase + (size_t)c * HW] = x1n + gma[c] * fo;
    }
  }
}

extern "C" void kernel_launch(void* const* d_in, const int* in_sizes, int n_in,
                              void* d_out, int out_size, void* d_ws, size_t ws_size,
                              hipStream_t stream) {
  (void)in_sizes; (void)n_in; (void)d_ws; (void)ws_size; (void)out_size;
  const float* x1    = (const float*)d_in[0];
  const float* x2    = (const float*)d_in[1];
  const float* q_w   = (const float*)d_in[2];
  const float* q_b   = (const float*)d_in[3];
  const float* k_w   = (const float*)d_in[4];
  const float* k_b   = (const float*)d_in[5];
  const float* v_w   = (const float*)d_in[6];
  const float* v_b   = (const float*)d_in[7];
  const float* bias  = (const float*)d_in[8];
  const float* sel_w = (const float*)d_in[9];
  const float* sel_b = (const float*)d_in[10];
  const float* fan_w = (const float*)d_in[11];
  const float* fan_b = (const float*)d_in[12];
  const float* gma   = (const float*)d_in[13];
  const float* ln1w  = (const float*)d_in[14];
  const float* ln1b  = (const float*)d_in[15];
  const float* ln2w  = (const float*)d_in[16];
  const float* ln2b  = (const float*)d_in[17];

  hipLaunchKernelGGL(cc_attn_kernel, dim3(4 * HH), dim3(BDIM), 0, stream,
                     x1, x2, q_w, q_b, k_w, k_b, v_w, v_b, bias, sel_w, sel_b,
                     fan_w, fan_b, gma, ln1w, ln1b, ln2w, ln2b,
                     (float*)d_out);
}

// Round 6
// 75.520 us; speedup vs baseline: 1.7308x; 1.2993x over previous
//
#include <hip/hip_runtime.h>

#define BDIM 512
#define HH 256
#define WW 256
#define NF 64
#define NH 8
#define HW (HH * WW)

typedef __attribute__((ext_vector_type(8))) short short8v;
typedef __attribute__((ext_vector_type(4))) float f32x4;

// round-to-nearest-even fp32 -> bf16 bits
__device__ __forceinline__ unsigned short f2bf(float f) {
  const unsigned u = __float_as_uint(f);
  return (unsigned short)((u + 0x7fffu + ((u >> 16) & 1u)) >> 16);
}

// exp2 of 4 fp32 -> packed 2x(2xbf16)
__device__ __forceinline__ uint2 exp2_pack(f32x4 sv) {
  const float e0 = __builtin_amdgcn_exp2f(sv.x);
  const float e1 = __builtin_amdgcn_exp2f(sv.y);
  const float e2 = __builtin_amdgcn_exp2f(sv.z);
  const float e3 = __builtin_amdgcn_exp2f(sv.w);
  uint2 r;
  r.x = (unsigned)f2bf(e0) | ((unsigned)f2bf(e1) << 16);
  r.y = (unsigned)f2bf(e2) | ((unsigned)f2bf(e3) << 16);
  return r;
}

struct __align__(16) Smem {
  unsigned short kb16[WW * 8];     // [u][d]  K bf16
  unsigned short qb16[WW * 8];     // [q][d]  Q bf16, pre-scaled by SCALE*log2e
  unsigned short vb16[8][264];     // [d][u]  V bf16 transposed, padded row
  unsigned short pstage[8][640];   // per-wave P^T staging: [16 q][40 u] bf16
  float mpst[WW][10];              // [q][ d0..7, l, pad ]
  float murst[WW][2];              // mu1, rstd1 per pixel
  float Sq1[NH], Sq0[NH], Sk1[NH], Sk0[NH], Sv1[NH], Sv0[NH], bsel[NH];
};

__global__ __launch_bounds__(BDIM, 8)
void cc_attn_kernel(const float* __restrict__ x1,
                    const float* __restrict__ x2,
                    const float* __restrict__ q_w,
                    const float* __restrict__ q_b,
                    const float* __restrict__ k_w,
                    const float* __restrict__ k_b,
                    const float* __restrict__ v_w,
                    const float* __restrict__ v_b,
                    const float* __restrict__ bias,
                    const float* __restrict__ sel_w,
                    const float* __restrict__ sel_b,
                    const float* __restrict__ fan_w,
                    const float* __restrict__ fan_b,
                    const float* __restrict__ gma,
                    const float* __restrict__ ln1w,
                    const float* __restrict__ ln1b,
                    const float* __restrict__ ln2w,
                    const float* __restrict__ ln2b,
                    float* __restrict__ out)
{
  __shared__ Smem s;
  const int tid  = threadIdx.x;
  const int role = tid >> 8;         // 0: x2/K side (waves 0-3), 1: x1/Q,V side
  const int pix  = tid & 255;
  const int b = blockIdx.x >> 8;
  const int h = blockIdx.x & 255;
  const size_t rowbase = ((size_t)(b * NF) * HH + h) * WW;
  const size_t base = rowbase + pix;

  // ---- per-head reduction constants (threads 0..7) ----
  if (tid < NH) {
    const int d = tid;
    float s1q = 0, s0q = 0, s1k = 0, s0k = 0, s1v = 0, s0v = 0, bs = 0;
    for (int c = 0; c < NF; c++) {
      const float qw = q_w[d * NF + c], kw = k_w[d * NF + c], vw = v_w[d * NF + c];
      s1q += ln1w[c] * qw; s0q += ln1b[c] * qw;
      s1k += ln2w[c] * kw; s0k += ln2b[c] * kw;
      s1v += ln1w[c] * vw; s0v += ln1b[c] * vw;
      bs  += bias[c] * sel_w[d * NF + c];
    }
    s.Sq1[d] = s1q; s.Sq0[d] = s0q + q_b[d];
    s.Sk1[d] = s1k; s.Sk0[d] = s0k + k_b[d];
    s.Sv1[d] = s1v; s.Sv0[d] = s0v + v_b[d];
    s.bsel[d] = bs + sel_b[d];
  }

  // ---- streaming projection pass (role-split) ----
  float sum = 0.f, ss = 0.f;
  float ta[NH] = {}, tb[NH] = {};
  if (role == 0) {
    const float* p = x2 + base;
    #pragma unroll 4
    for (int c = 0; c < NF; c++) {
      const float xv = p[(size_t)c * HW];
      const float yv = xv * ln2w[c];
      sum += xv; ss += xv * xv;
      #pragma unroll
      for (int d = 0; d < NH; d++) ta[d] += yv * k_w[d * NF + c];
    }
  } else {
    const float* p = x1 + base;
    #pragma unroll 4
    for (int c = 0; c < NF; c++) {
      const float xv = p[(size_t)c * HW];
      const float yv = xv * ln1w[c];
      sum += xv; ss += xv * xv;
      #pragma unroll
      for (int d = 0; d < NH; d++) {
        ta[d] += yv * q_w[d * NF + c];
        tb[d] += yv * v_w[d * NF + c];
      }
    }
  }
  const float mu   = sum * (1.f / NF);
  const float rstd = rsqrtf(ss * (1.f / NF) - mu * mu + 1e-5f);
  if (role == 1) { s.murst[pix][0] = mu; s.murst[pix][1] = rstd; }

  __syncthreads();   // #1: head consts ready

  const float QS = 0.125f * 1.44269504088896340736f;  // SCALE * log2(e)
  if (role == 0) {
    unsigned short pk[8];
    #pragma unroll
    for (int d = 0; d < NH; d++)
      pk[d] = f2bf(rstd * (ta[d] - mu * s.Sk1[d]) + s.Sk0[d]);
    *reinterpret_cast<short8v*>(&s.kb16[pix * 8]) = *reinterpret_cast<short8v*>(pk);
  } else {
    unsigned short pk[8];
    #pragma unroll
    for (int d = 0; d < NH; d++) {
      pk[d] = f2bf((rstd * (ta[d] - mu * s.Sq1[d]) + s.Sq0[d]) * QS);
      s.vb16[d][pix] = f2bf(rstd * (tb[d] - mu * s.Sv1[d]) + s.Sv0[d]);
    }
    *reinterpret_cast<short8v*>(&s.qb16[pix * 8]) = *reinterpret_cast<short8v*>(pk);
  }

  __syncthreads();   // #2: K/Q/V staged

  // ---- MFMA attention: S^T = K·Q^T, P = exp2(S^T), O^T = V^T·P^T ----
  {
    const int lane = tid & 63;
    const int wid  = tid >> 6;          // 8 waves, each owns 32 q columns
    const int g    = lane >> 4;
    const int r16  = lane & 15;
    const int qb0  = wid * 32;

    const short8v zero8 = {0,0,0,0,0,0,0,0};
    const short8v ones8 = {(short)0x3F80,(short)0x3F80,(short)0x3F80,(short)0x3F80,
                           (short)0x3F80,(short)0x3F80,(short)0x3F80,(short)0x3F80};
    const f32x4 zero4 = {0.f, 0.f, 0.f, 0.f};

    // B-frags of Q (constant across chunks); only k-group 0 is real (k=8 pad 32)
    short8v bq0 = zero8, bq1 = zero8;
    if (g == 0) {
      bq0 = *reinterpret_cast<const short8v*>(&s.qb16[(qb0 + r16) * 8]);
      bq1 = *reinterpret_cast<const short8v*>(&s.qb16[(qb0 + 16 + r16) * 8]);
    }

    f32x4 o0 = zero4, o1 = zero4;      // O^T accum for q-tiles 0,1
    unsigned short* __restrict__ pst = &s.pstage[wid][0];
    const int wr_off = r16 * 40 + g * 4;   // P^T write base (ushort idx), +t*16
    const int rd_off = r16 * 40 + g * 8;   // P^T read base (ushort idx)

    #pragma unroll 2
    for (int ch = 0; ch < 8; ++ch) {
      const int u0 = ch * 32;
      // A-frags of K for the two u-tiles (k-group 0 only)
      short8v ak0 = zero8, ak1 = zero8;
      if (g == 0) {
        ak0 = *reinterpret_cast<const short8v*>(&s.kb16[(u0 + r16) * 8]);
        ak1 = *reinterpret_cast<const short8v*>(&s.kb16[(u0 + 16 + r16) * 8]);
      }
      // A-frag of V^T: rows d=0..7 real, row 8 = ones (denominator), rest 0
      short8v av = zero8;
      if (r16 < 8)       av = *reinterpret_cast<const short8v*>(&s.vb16[r16][u0 + g * 8]);
      else if (r16 == 8) av = ones8;

      // ----- q-tile 0 -----
      {
        f32x4 s0 = __builtin_amdgcn_mfma_f32_16x16x32_bf16(ak0, bq0, zero4, 0, 0, 0);
        f32x4 s1 = __builtin_amdgcn_mfma_f32_16x16x32_bf16(ak1, bq0, zero4, 0, 0, 0);
        const uint2 p0 = exp2_pack(s0);
        const uint2 p1 = exp2_pack(s1);
        *reinterpret_cast<uint2*>(&pst[wr_off])      = p0;   // u-tile 0
        *reinterpret_cast<uint2*>(&pst[wr_off + 16]) = p1;   // u-tile 1
        const short8v bp = *reinterpret_cast<const short8v*>(&pst[rd_off]);
        o0 = __builtin_amdgcn_mfma_f32_16x16x32_bf16(av, bp, o0, 0, 0, 0);
      }
      // ----- q-tile 1 -----
      {
        f32x4 s0 = __builtin_amdgcn_mfma_f32_16x16x32_bf16(ak0, bq1, zero4, 0, 0, 0);
        f32x4 s1 = __builtin_amdgcn_mfma_f32_16x16x32_bf16(ak1, bq1, zero4, 0, 0, 0);
        const uint2 p0 = exp2_pack(s0);
        const uint2 p1 = exp2_pack(s1);
        *reinterpret_cast<uint2*>(&pst[wr_off])      = p0;
        *reinterpret_cast<uint2*>(&pst[wr_off + 16]) = p1;
        const short8v bp = *reinterpret_cast<const short8v*>(&pst[rd_off]);
        o1 = __builtin_amdgcn_mfma_f32_16x16x32_bf16(av, bp, o1, 0, 0, 0);
      }
    }

    // write O^T frags: lane holds q-col = r16, d-rows = g*4+reg
    {
      const int q0 = qb0 + r16;
      const int q1 = qb0 + 16 + r16;
      if (g == 0) {
        *reinterpret_cast<float2*>(&s.mpst[q0][0]) = make_float2(o0.x, o0.y);
        *reinterpret_cast<float2*>(&s.mpst[q0][2]) = make_float2(o0.z, o0.w);
        *reinterpret_cast<float2*>(&s.mpst[q1][0]) = make_float2(o1.x, o1.y);
        *reinterpret_cast<float2*>(&s.mpst[q1][2]) = make_float2(o1.z, o1.w);
      } else if (g == 1) {
        *reinterpret_cast<float2*>(&s.mpst[q0][4]) = make_float2(o0.x, o0.y);
        *reinterpret_cast<float2*>(&s.mpst[q0][6]) = make_float2(o0.z, o0.w);
        *reinterpret_cast<float2*>(&s.mpst[q1][4]) = make_float2(o1.x, o1.y);
        *reinterpret_cast<float2*>(&s.mpst[q1][6]) = make_float2(o1.z, o1.w);
      } else if (g == 2) {
        s.mpst[q0][8] = o0.x;    // denominator l (row d=8)
        s.mpst[q1][8] = o1.x;
      }
    }
  }

  __syncthreads();   // #3: O^T + l staged

  // ---- epilogue: softmax divide + bias-sel, fan-out + gated residual ----
  {
    const int qg = pix;
    const float rl = 1.0f / s.mpst[qg][8];
    float mp[NH];
    #pragma unroll
    for (int d = 0; d < NH; d++) mp[d] = s.mpst[qg][d] * rl + s.bsel[d];

    const float m1 = s.murst[qg][0];
    const float r1 = s.murst[qg][1];
    const int c0 = role * 32;
    const float* p = x1 + base;   // base == rowbase + qg
    #pragma unroll 4
    for (int cc = 0; cc < 32; cc++) {
      const int c = c0 + cc;
      float fo = fan_b[c];
      #pragma unroll
      for (int d = 0; d < NH; d++) fo += mp[d] * fan_w[c * NH + d];
      const float xv  = p[(size_t)c * HW];
      const float x1n = (xv - m1) * r1 * ln1w[c] + ln1b[c];
      out[base + (size_t)c * HW] = x1n + gma[c] * fo;
    }
  }
}

extern "C" void kernel_launch(void* const* d_in, const int* in_sizes, int n_in,
                              void* d_out, int out_size, void* d_ws, size_t ws_size,
                              hipStream_t stream) {
  (void)in_sizes; (void)n_in; (void)d_ws; (void)ws_size; (void)out_size;
  const float* x1    = (const float*)d_in[0];
  const float* x2    = (const float*)d_in[1];
  const float* q_w   = (const float*)d_in[2];
  const float* q_b   = (const float*)d_in[3];
  const float* k_w   = (const float*)d_in[4];
  const float* k_b   = (const float*)d_in[5];
  const float* v_w   = (const float*)d_in[6];
  const float* v_b   = (const float*)d_in[7];
  const float* bias  = (const float*)d_in[8];
  const float* sel_w = (const float*)d_in[9];
  const float* sel_b = (const float*)d_in[10];
  const float* fan_w = (const float*)d_in[11];
  const float* fan_b = (const float*)d_in[12];
  const float* gma   = (const float*)d_in[13];
  const float* ln1w  = (const float*)d_in[14];
  const float* ln1b  = (const float*)d_in[15];
  const float* ln2w  = (const float*)d_in[16];
  const float* ln2b  = (const float*)d_in[17];

  hipLaunchKernelGGL(cc_attn_kernel, dim3(4 * HH), dim3(BDIM), 0, stream,
                     x1, x2, q_w, q_b, k_w, k_b, v_w, v_b, bias, sel_w, sel_b,
                     fan_w, fan_b, gma, ln1w, ln1b, ln2w, ln2b,
                     (float*)d_out);
}